// Round 1
// baseline (211.369 us; speedup 1.0000x reference)
//
#include <hip/hip_runtime.h>
#include <math.h>

#define TAU_MIN 0.02f
#define TAU_MAX 2.0f
#define LN_EPS  1e-5f

struct Params {
    float tau, inv_tau;
    float lnw[3], lnb[3];
    float w1[16][3];
    float b1[16];
    float w2[3][16];
    float b2[3];
};

__device__ __forceinline__ float row_eval(float x0, float x1, float x2, const Params& p)
{
    // soft-min: best = -tau * logsumexp(-x/tau) = m - tau*log(sum exp((m-x)/tau)), m = min(x)
    float m  = fminf(x0, fminf(x1, x2));
    float e0 = __expf((m - x0) * p.inv_tau);
    float e1 = __expf((m - x1) * p.inv_tau);
    float e2 = __expf((m - x2) * p.inv_tau);
    float best = fmaf(-p.tau, __logf(e0 + e1 + e2), m);

    // feats = -|x - best|
    float f0 = -fabsf(x0 - best);
    float f1 = -fabsf(x1 - best);
    float f2 = -fabsf(x2 - best);

    // LayerNorm over 3 + affine
    float mu  = (f0 + f1 + f2) * (1.0f / 3.0f);
    float d0 = f0 - mu, d1 = f1 - mu, d2 = f2 - mu;
    float var = fmaf(d0, d0, fmaf(d1, d1, d2 * d2)) * (1.0f / 3.0f);
    float rs  = __builtin_amdgcn_rsqf(var + LN_EPS);
    float h0 = fmaf(d0 * rs, p.lnw[0], p.lnb[0]);
    float h1 = fmaf(d1 * rs, p.lnw[1], p.lnb[1]);
    float h2 = fmaf(d2 * rs, p.lnw[2], p.lnb[2]);

    // Linear(3->16) + ReLU, fused with Linear(16->3)
    float l0 = p.b2[0], l1 = p.b2[1], l2 = p.b2[2];
#pragma unroll
    for (int j = 0; j < 16; ++j) {
        float hj = fmaf(h2, p.w1[j][2], fmaf(h1, p.w1[j][1], fmaf(h0, p.w1[j][0], p.b1[j])));
        hj = fmaxf(hj, 0.0f);
        l0 = fmaf(hj, p.w2[0][j], l0);
        l1 = fmaf(hj, p.w2[1][j], l1);
        l2 = fmaf(hj, p.w2[2][j], l2);
    }

    // softmax(3) + weighted sum
    float lm = fmaxf(l0, fmaxf(l1, l2));
    float s0 = __expf(l0 - lm);
    float s1 = __expf(l1 - lm);
    float s2 = __expf(l2 - lm);
    float r  = __builtin_amdgcn_rcpf(s0 + s1 + s2);
    return fmaf(x0, s0, fmaf(x1, s1, x2 * s2)) * r;
}

__global__ __launch_bounds__(256) void nn2_softmin_kernel(
    const float* __restrict__ x,
    const float* __restrict__ lnw_g, const float* __restrict__ lnb_g,
    const float* __restrict__ w1_g,  const float* __restrict__ b1_g,
    const float* __restrict__ w2_g,  const float* __restrict__ b2_g,
    const float* __restrict__ ltau_g,
    float* __restrict__ out, int nrows)
{
    long long g    = (long long)blockIdx.x * blockDim.x + threadIdx.x;
    long long base = g * 4;
    if (base >= nrows) return;

    Params p;
    p.tau     = fminf(fmaxf(__expf(ltau_g[0]), TAU_MIN), TAU_MAX);
    p.inv_tau = 1.0f / p.tau;
#pragma unroll
    for (int c = 0; c < 3; ++c) {
        p.lnw[c] = lnw_g[c];
        p.lnb[c] = lnb_g[c];
        p.b2[c]  = b2_g[c];
    }
#pragma unroll
    for (int j = 0; j < 16; ++j) {
        p.b1[j] = b1_g[j];
#pragma unroll
        for (int c = 0; c < 3; ++c) p.w1[j][c] = w1_g[j * 3 + c];
    }
#pragma unroll
    for (int c = 0; c < 3; ++c)
#pragma unroll
        for (int j = 0; j < 16; ++j) p.w2[c][j] = w2_g[c * 16 + j];

    if (base + 4 <= nrows) {
        // 4 rows = 12 floats = 3 float4 loads (fully coalesced, 16B/lane)
        const float4* x4 = reinterpret_cast<const float4*>(x);
        float4 va = x4[g * 3 + 0];
        float4 vb = x4[g * 3 + 1];
        float4 vc = x4[g * 3 + 2];
        float4 o;
        o.x = row_eval(va.x, va.y, va.z, p);
        o.y = row_eval(va.w, vb.x, vb.y, p);
        o.z = row_eval(vb.z, vb.w, vc.x, p);
        o.w = row_eval(vc.y, vc.z, vc.w, p);
        reinterpret_cast<float4*>(out)[g] = o;
    } else {
        // scalar tail (nrows not a multiple of 4)
        for (long long r = base; r < nrows; ++r)
            out[r] = row_eval(x[r * 3 + 0], x[r * 3 + 1], x[r * 3 + 2], p);
    }
}

extern "C" void kernel_launch(void* const* d_in, const int* in_sizes, int n_in,
                              void* d_out, int out_size, void* d_ws, size_t ws_size,
                              hipStream_t stream) {
    const float* x    = (const float*)d_in[0];
    const float* lnw  = (const float*)d_in[1];
    const float* lnb  = (const float*)d_in[2];
    const float* w1   = (const float*)d_in[3];
    const float* b1   = (const float*)d_in[4];
    const float* w2   = (const float*)d_in[5];
    const float* b2   = (const float*)d_in[6];
    const float* ltau = (const float*)d_in[7];
    float* out = (float*)d_out;

    int nrows   = out_size;                 // N
    int ngroups = (nrows + 3) / 4;          // 4 rows per thread
    int block   = 256;
    int grid    = (ngroups + block - 1) / block;

    nn2_softmin_kernel<<<grid, block, 0, stream>>>(x, lnw, lnb, w1, b1, w2, b2, ltau,
                                                   out, nrows);
}

// Round 2
// 90.029 us; speedup vs baseline: 2.3478x; 2.3478x over previous
//
#include <hip/hip_runtime.h>
#include <math.h>

#define TAU_MIN 0.02f
#define TAU_MAX 2.0f
#define LN_EPS  1e-5f

// One thread processes 4 rows. Weights are loaded at point-of-use with
// compile-time-constant offsets from wave-uniform pointers -> scalar loads
// (SGPR, scalar cache), short live ranges, no scratch spill. The j-loop
// spans all 4 rows so each weight scalar is reused 4x.
__global__ __launch_bounds__(256) void nn2_softmin_kernel(
    const float* __restrict__ x,
    const float* __restrict__ lnw_g, const float* __restrict__ lnb_g,
    const float* __restrict__ w1_g,  const float* __restrict__ b1_g,
    const float* __restrict__ w2_g,  const float* __restrict__ b2_g,
    const float* __restrict__ ltau_g,
    float* __restrict__ out, int nrows)
{
    int g = blockIdx.x * blockDim.x + threadIdx.x;
    long long base = (long long)g * 4;
    if (base >= nrows) return;

    const float tau = fminf(fmaxf(__expf(ltau_g[0]), TAU_MIN), TAU_MAX);
    const float it  = 1.0f / tau;
    const float lw0 = lnw_g[0], lw1 = lnw_g[1], lw2 = lnw_g[2];
    const float lb0 = lnb_g[0], lb1 = lnb_g[1], lb2 = lnb_g[2];

    // ---- load 4 rows (3x float4 = 48B contiguous per thread) ----
    float X[4][3];
    if (base + 4 <= nrows) {
        const float4* x4 = reinterpret_cast<const float4*>(x) + (long long)g * 3;
        float4 va = x4[0], vb = x4[1], vc = x4[2];
        X[0][0]=va.x; X[0][1]=va.y; X[0][2]=va.z;
        X[1][0]=va.w; X[1][1]=vb.x; X[1][2]=vb.y;
        X[2][0]=vb.z; X[2][1]=vb.w; X[2][2]=vc.x;
        X[3][0]=vc.y; X[3][1]=vc.z; X[3][2]=vc.w;
    } else {
#pragma unroll
        for (int r = 0; r < 4; ++r) {
            long long rr = (base + r < nrows) ? base + r : (long long)nrows - 1;
            X[r][0]=x[rr*3]; X[r][1]=x[rr*3+1]; X[r][2]=x[rr*3+2];
        }
    }

    // ---- stage A: softmin -> feats -> LayerNorm(3), per row ----
    float H[4][3];
#pragma unroll
    for (int r = 0; r < 4; ++r) {
        float x0 = X[r][0], x1 = X[r][1], x2 = X[r][2];
        float m  = fminf(x0, fminf(x1, x2));
        float e0 = __expf((m - x0) * it);
        float e1 = __expf((m - x1) * it);
        float e2 = __expf((m - x2) * it);
        float best = fmaf(-tau, __logf(e0 + e1 + e2), m);
        float f0 = -fabsf(x0 - best);
        float f1 = -fabsf(x1 - best);
        float f2 = -fabsf(x2 - best);
        float mu = (f0 + f1 + f2) * (1.0f / 3.0f);
        float d0 = f0 - mu, d1 = f1 - mu, d2 = f2 - mu;
        float var = fmaf(d0, d0, fmaf(d1, d1, d2 * d2)) * (1.0f / 3.0f);
        float rs  = __builtin_amdgcn_rsqf(var + LN_EPS);
        H[r][0] = fmaf(d0 * rs, lw0, lb0);
        H[r][1] = fmaf(d1 * rs, lw1, lb1);
        H[r][2] = fmaf(d2 * rs, lw2, lb2);
    }

    // ---- stage B: Linear(3->16)+ReLU fused into Linear(16->3) ----
    float L[4][3];
    {
        const float b20 = b2_g[0], b21 = b2_g[1], b22 = b2_g[2];
#pragma unroll
        for (int r = 0; r < 4; ++r) { L[r][0] = b20; L[r][1] = b21; L[r][2] = b22; }
    }

#pragma unroll
    for (int j = 0; j < 16; ++j) {
        const float a0 = w1_g[3*j + 0];
        const float a1 = w1_g[3*j + 1];
        const float a2 = w1_g[3*j + 2];
        const float bj = b1_g[j];
        const float u0 = w2_g[j];
        const float u1 = w2_g[16 + j];
        const float u2 = w2_g[32 + j];
#pragma unroll
        for (int r = 0; r < 4; ++r) {
            float hj = fmaf(H[r][2], a2, fmaf(H[r][1], a1, fmaf(H[r][0], a0, bj)));
            hj = fmaxf(hj, 0.0f);
            L[r][0] = fmaf(hj, u0, L[r][0]);
            L[r][1] = fmaf(hj, u1, L[r][1]);
            L[r][2] = fmaf(hj, u2, L[r][2]);
        }
    }

    // ---- stage C: softmax(3) + weighted sum ----
    float O[4];
#pragma unroll
    for (int r = 0; r < 4; ++r) {
        float l0 = L[r][0], l1 = L[r][1], l2 = L[r][2];
        float lm = fmaxf(l0, fmaxf(l1, l2));
        float s0 = __expf(l0 - lm);
        float s1 = __expf(l1 - lm);
        float s2 = __expf(l2 - lm);
        float rc = __builtin_amdgcn_rcpf(s0 + s1 + s2);
        O[r] = fmaf(X[r][0], s0, fmaf(X[r][1], s1, X[r][2] * s2)) * rc;
    }

    if (base + 4 <= nrows) {
        float4 o; o.x = O[0]; o.y = O[1]; o.z = O[2]; o.w = O[3];
        reinterpret_cast<float4*>(out)[g] = o;
    } else {
        for (int r = 0; r < 4 && base + r < nrows; ++r) out[base + r] = O[r];
    }
}

extern "C" void kernel_launch(void* const* d_in, const int* in_sizes, int n_in,
                              void* d_out, int out_size, void* d_ws, size_t ws_size,
                              hipStream_t stream) {
    const float* x    = (const float*)d_in[0];
    const float* lnw  = (const float*)d_in[1];
    const float* lnb  = (const float*)d_in[2];
    const float* w1   = (const float*)d_in[3];
    const float* b1   = (const float*)d_in[4];
    const float* w2   = (const float*)d_in[5];
    const float* b2   = (const float*)d_in[6];
    const float* ltau = (const float*)d_in[7];
    float* out = (float*)d_out;

    int nrows   = out_size;
    int ngroups = (nrows + 3) / 4;
    int block   = 256;
    int grid    = (ngroups + block - 1) / block;

    nn2_softmin_kernel<<<grid, block, 0, stream>>>(x, lnw, lnb, w1, b1, w2, b2, ltau,
                                                   out, nrows);
}

// Round 3
// 69.290 us; speedup vs baseline: 3.0505x; 1.2993x over previous
//
#include <hip/hip_runtime.h>
#include <math.h>

#define LN_EPS 1e-5f

// KEY IDENTITY: best = m - tau*log(sum exp((m-x_i)/tau)) <= m <= x_i  (sum>=1),
// so feats_i = -|x_i-best| = best - x_i, and LayerNorm is shift-invariant:
//   feats - mean(feats) = mean(x) - x_i,  var(feats) = var(x).
// The whole softmin/tau stage cancels exactly; h = (mean_x - x)*rsqrt(var_x+eps)*lnw + lnb.
// One thread = 4 rows (3x float4 in, 1x float4 out). Weights are wave-uniform
// point-of-use scalar loads; j-loop spans all 4 rows for 4x SGPR reuse.
__global__ __launch_bounds__(256) void nn2_softmin_kernel(
    const float* __restrict__ x,
    const float* __restrict__ lnw_g, const float* __restrict__ lnb_g,
    const float* __restrict__ w1_g,  const float* __restrict__ b1_g,
    const float* __restrict__ w2_g,  const float* __restrict__ b2_g,
    float* __restrict__ out, int nrows)
{
    int g = blockIdx.x * blockDim.x + threadIdx.x;
    long long base = (long long)g * 4;
    if (base >= nrows) return;

    const float lw0 = lnw_g[0], lw1 = lnw_g[1], lw2 = lnw_g[2];
    const float lb0 = lnb_g[0], lb1 = lnb_g[1], lb2 = lnb_g[2];

    // ---- load 4 rows (48B contiguous per thread) ----
    float X[4][3];
    if (base + 4 <= nrows) {
        const float4* x4 = reinterpret_cast<const float4*>(x) + (long long)g * 3;
        float4 va = x4[0], vb = x4[1], vc = x4[2];
        X[0][0]=va.x; X[0][1]=va.y; X[0][2]=va.z;
        X[1][0]=va.w; X[1][1]=vb.x; X[1][2]=vb.y;
        X[2][0]=vb.z; X[2][1]=vb.w; X[2][2]=vc.x;
        X[3][0]=vc.y; X[3][1]=vc.z; X[3][2]=vc.w;
    } else {
#pragma unroll
        for (int r = 0; r < 4; ++r) {
            long long rr = (base + r < nrows) ? base + r : (long long)nrows - 1;
            X[r][0]=x[rr*3]; X[r][1]=x[rr*3+1]; X[r][2]=x[rr*3+2];
        }
    }

    // ---- LayerNorm directly on x (softmin cancels; see header comment) ----
    float H[4][3];
#pragma unroll
    for (int r = 0; r < 4; ++r) {
        float x0 = X[r][0], x1 = X[r][1], x2 = X[r][2];
        float mu = (x0 + x1 + x2) * (1.0f / 3.0f);
        float d0 = mu - x0, d1 = mu - x1, d2 = mu - x2;
        float sse = fmaf(d0, d0, fmaf(d1, d1, d2 * d2));
        float rs  = __builtin_amdgcn_rsqf(fmaf(sse, 1.0f / 3.0f, LN_EPS));
        H[r][0] = fmaf(d0 * rs, lw0, lb0);
        H[r][1] = fmaf(d1 * rs, lw1, lb1);
        H[r][2] = fmaf(d2 * rs, lw2, lb2);
    }

    // ---- Linear(3->16)+ReLU fused into Linear(16->3) ----
    float L[4][3];
    {
        const float b20 = b2_g[0], b21 = b2_g[1], b22 = b2_g[2];
#pragma unroll
        for (int r = 0; r < 4; ++r) { L[r][0] = b20; L[r][1] = b21; L[r][2] = b22; }
    }

#pragma unroll
    for (int j = 0; j < 16; ++j) {
        const float a0 = w1_g[3*j + 0];
        const float a1 = w1_g[3*j + 1];
        const float a2 = w1_g[3*j + 2];
        const float bj = b1_g[j];
        const float u0 = w2_g[j];
        const float u1 = w2_g[16 + j];
        const float u2 = w2_g[32 + j];
#pragma unroll
        for (int r = 0; r < 4; ++r) {
            float hj = fmaf(H[r][2], a2, fmaf(H[r][1], a1, fmaf(H[r][0], a0, bj)));
            hj = fmaxf(hj, 0.0f);
            L[r][0] = fmaf(hj, u0, L[r][0]);
            L[r][1] = fmaf(hj, u1, L[r][1]);
            L[r][2] = fmaf(hj, u2, L[r][2]);
        }
    }

    // ---- softmax(3) + weighted sum ----
    float O[4];
#pragma unroll
    for (int r = 0; r < 4; ++r) {
        float l0 = L[r][0], l1 = L[r][1], l2 = L[r][2];
        float lm = fmaxf(l0, fmaxf(l1, l2));   // -> v_max3 path
        float s0 = __expf(l0 - lm);
        float s1 = __expf(l1 - lm);
        float s2 = __expf(l2 - lm);
        float rc = __builtin_amdgcn_rcpf(s0 + s1 + s2);
        O[r] = fmaf(X[r][0], s0, fmaf(X[r][1], s1, X[r][2] * s2)) * rc;
    }

    if (base + 4 <= nrows) {
        float4 o; o.x = O[0]; o.y = O[1]; o.z = O[2]; o.w = O[3];
        reinterpret_cast<float4*>(out)[g] = o;
    } else {
        for (int r = 0; r < 4 && base + r < nrows; ++r) out[base + r] = O[r];
    }
}

extern "C" void kernel_launch(void* const* d_in, const int* in_sizes, int n_in,
                              void* d_out, int out_size, void* d_ws, size_t ws_size,
                              hipStream_t stream) {
    const float* x    = (const float*)d_in[0];
    const float* lnw  = (const float*)d_in[1];
    const float* lnb  = (const float*)d_in[2];
    const float* w1   = (const float*)d_in[3];
    const float* b1   = (const float*)d_in[4];
    const float* w2   = (const float*)d_in[5];
    const float* b2   = (const float*)d_in[6];
    // d_in[7] (log_tau) is mathematically dead: softmin cancels in LayerNorm.
    float* out = (float*)d_out;

    int nrows   = out_size;
    int ngroups = (nrows + 3) / 4;
    int block   = 256;
    int grid    = (ngroups + block - 1) / block;

    nn2_softmin_kernel<<<grid, block, 0, stream>>>(x, lnw, lnb, w1, b1, w2, b2,
                                                   out, nrows);
}